// Round 10
// baseline (441.432 us; speedup 1.0000x reference)
//
#include <hip/hip_runtime.h>
#include <hip/hip_bf16.h>

#define NPTS 8192
#define KNN 64
#define EPSF 1e-7f

// ---------------- workspace layout (float offsets) ----------------
#define OFF_P4      0              // packed (x,y,z,rr) float4 per point: 4*N
#define OFF_STATS   32768          // s1:+0(128) s2:+128(256) s3:+384(512) s4:+896(2048) = 2944
#define OFF_AVEC    36000          // 9 floats a1,a2,a3
#define OFF_PART    36012          // 32 blocks x 2 u64 = 128 floats
#define OFF_FEATDN  36864          // N*4 -> 69632
#define OFF_WT1     69632          // 4*64 fp32 transposed -> 69888
#define OFF_GWT     69888          // MLP bf16 weights
#define OFF_BW2     79104          // c2w bf16
#define OFF_BW3     83200          // c3w bf16
#define OFF_BW4     107776         // c4w bf16
#define OFF_XB1     238848         // bf16 [8192][64]
#define OFF_XB3     500992         // bf16 [8192][192]
#define OFF_XB4     1287424        // bf16 [8192][256]
#define OFF_Y1      2336000        // 64*N fp32 (hosts KNN-phase scratch before conv1)
#define OFF_Y2      2860288        // 128*N fp32
#define OFF_Y3      3908864        // 256*N fp32
#define OFF_FEATUP  6006016        // N*K uint2 (packed bf16 feats) = 1048576 floats

// KNN-phase scratch parked inside Y1 (dead until conv1 runs, after knn completes)
#define OFF_P4S     OFF_Y1             // x-window-sorted, y-sorted-within-window; w = as_float(origIdx)
#define OFF_TBND    (OFF_Y1 + 32768)   // per-window [xmin,xmax]: 16 floats
#define OFF_SBND    (OFF_Y1 + 32784)   // per-subtile [ymin,ymax]: 128*2 = 256 floats
#define OFF_BCNT    (OFF_Y1 + 33100)   // 64 bin counts (int)
#define OFF_BOFS    (OFF_Y1 + 33164)   // 65 bin offsets (int)
#define OFF_BFIL    (OFF_Y1 + 33232)   // 64 bin fill cursors (int)

typedef __bf16 bf16x8 __attribute__((ext_vector_type(8)));
typedef float  f32x4  __attribute__((ext_vector_type(4)));

__device__ __forceinline__ unsigned f2u(float f) {
    unsigned u = __float_as_uint(f);
    return ((int)u >= 0) ? (u | 0x80000000u) : ~u;
}
__device__ __forceinline__ float key_to_f(unsigned long long k) {
    unsigned v = (unsigned)(k >> 32);
    unsigned ob = (v & 0x80000000u) ? (v ^ 0x80000000u) : ~v;
    return __uint_as_float(ob);
}
__device__ __forceinline__ unsigned short f2bf(float x) {
    unsigned u = __float_as_uint(x);
    unsigned r = (u + 0x7FFFu + ((u >> 16) & 1u)) >> 16;   // RNE
    return (unsigned short)r;
}
__device__ __forceinline__ unsigned long long u64min(unsigned long long a, unsigned long long b){ return a < b ? a : b; }
__device__ __forceinline__ unsigned long long u64max(unsigned long long a, unsigned long long b){ return a < b ? b : a; }

__device__ __forceinline__ unsigned long long sort_merge(
    unsigned long long key, unsigned long long cur, int lane)
{
    #pragma unroll
    for (int k = 2; k <= 64; k <<= 1) {
        #pragma unroll
        for (int j = k >> 1; j > 0; j >>= 1) {
            unsigned long long o = __shfl_xor(key, j);
            bool up = ((lane & k) == 0);
            bool lower = ((lane & j) == 0);
            key = (lower == up) ? u64min(key, o) : u64max(key, o);
        }
    }
    unsigned long long rev = __shfl(key, 63 - lane);
    unsigned long long m = u64min(cur, rev);
    #pragma unroll
    for (int j = 32; j > 0; j >>= 1) {
        unsigned long long o = __shfl_xor(m, j);
        m = ((lane & j) == 0) ? u64min(m, o) : u64max(m, o);
    }
    return m;
}

__device__ __forceinline__ int bin9(float x) {
    int b = (int)((x + 4.5f) * (64.0f / 9.0f));
    return min(63, max(0, b));
}

// ---------------- prep A: p4, x-histogram, argmax/argmin partials ----------------
__global__ __launch_bounds__(256) void prep_a_kernel(
    const float* __restrict__ points, float* __restrict__ ws)
{
    const int n = blockIdx.x * 256 + threadIdx.x;
    float x = points[3*n+0], y = points[3*n+1], z = points[3*n+2];
    float rr = x*x + y*y + z*z;
    ((float4*)(ws + OFF_P4))[n] = make_float4(x, y, z, rr);
    atomicAdd((int*)(ws + OFF_BCNT) + bin9(x), 1);
    float vn = sqrtf(rr);
    unsigned b = __float_as_uint(vn);
    unsigned long long mxk = ((unsigned long long)b << 32) | (unsigned long long)(0xFFFFFFFFu - (unsigned)n);
    unsigned long long mnk = ((unsigned long long)b << 32) | (unsigned long long)(unsigned)n;
    for (int j = 32; j > 0; j >>= 1) {
        mxk = u64max(mxk, __shfl_xor(mxk, j));
        mnk = u64min(mnk, __shfl_xor(mnk, j));
    }
    __shared__ unsigned long long smx[4], smn[4];
    int wid = threadIdx.x >> 6;
    if ((threadIdx.x & 63) == 0) { smx[wid] = mxk; smn[wid] = mnk; }
    __syncthreads();
    if (threadIdx.x == 0) {
        unsigned long long MX = 0ull, MN = ~0ull;
        for (int i = 0; i < 4; ++i) { MX = u64max(MX, smx[i]); MN = u64min(MN, smn[i]); }
        unsigned long long* parts = (unsigned long long*)(ws + OFF_PART);
        parts[2*blockIdx.x + 0] = MX;
        parts[2*blockIdx.x + 1] = MN;
    }
}

// ---------------- prep B: reduce partials -> a1/a2/a3; bin prefix sums ----------------
__global__ __launch_bounds__(64) void prep_b_kernel(
    const float* __restrict__ points, float* __restrict__ ws)
{
    const int lane = threadIdx.x;
    const unsigned long long* parts = (const unsigned long long*)(ws + OFF_PART);
    unsigned long long mxk = (lane < 32) ? parts[2*lane + 0] : 0ull;
    unsigned long long mnk = (lane < 32) ? parts[2*lane + 1] : ~0ull;
    for (int j = 32; j > 0; j >>= 1) {
        mxk = u64max(mxk, __shfl_xor(mxk, j));
        mnk = u64min(mnk, __shfl_xor(mnk, j));
    }
    if (lane == 0) {
        int i1 = (int)(0xFFFFFFFFu - (unsigned)(mxk & 0xFFFFFFFFu));
        int i2 = (int)(unsigned)(mnk & 0xFFFFFFFFu);
        float a1x = points[3*i1+0], a1y = points[3*i1+1], a1z = points[3*i1+2];
        float n1 = sqrtf(a1x*a1x + a1y*a1y + a1z*a1z) + EPSF;
        a1x /= n1; a1y /= n1; a1z /= n1;
        float a2x = points[3*i2+0], a2y = points[3*i2+1], a2z = points[3*i2+2];
        float n2 = sqrtf(a2x*a2x + a2y*a2y + a2z*a2z) + EPSF;
        a2x /= n2; a2y /= n2; a2z /= n2;
        float a3x = a1x + 1.5f*a2x, a3y = a1y + 1.5f*a2y, a3z = a1z + 1.5f*a2z;
        float n3 = sqrtf(a3x*a3x + a3y*a3y + a3z*a3z) + EPSF;
        a3x /= n3; a3y /= n3; a3z /= n3;
        float* av = ws + OFF_AVEC;
        av[0]=a1x; av[1]=a1y; av[2]=a1z;
        av[3]=a2x; av[4]=a2y; av[5]=a2z;
        av[6]=a3x; av[7]=a3y; av[8]=a3z;
    }
    if (lane == 1) {
        const int* cnt = (const int*)(ws + OFF_BCNT);
        int* ofs = (int*)(ws + OFF_BOFS);
        int* fil = (int*)(ws + OFF_BFIL);
        int acc = 0;
        for (int i = 0; i < 64; ++i) { ofs[i] = acc; fil[i] = acc; acc += cnt[i]; }
        ofs[64] = acc;
    }
}

// ---------------- prep C+scatter: feat_down, counting-sort by x-bin ----------------
__global__ __launch_bounds__(256) void prep_cs_kernel(float* __restrict__ ws)
{
    const int n = blockIdx.x * 256 + threadIdx.x;
    const float* av = ws + OFF_AVEC;
    float4 v = ((const float4*)(ws + OFF_P4))[n];
    float vn = sqrtf(v.w);
    float den = vn + EPSF;
    float f1 = (v.x*av[0] + v.y*av[1] + v.z*av[2]) / den;
    float f2 = (v.x*av[3] + v.y*av[4] + v.z*av[5]) / den;
    float f3 = (v.x*av[6] + v.y*av[7] + v.z*av[8]) / den;
    ((float4*)(ws + OFF_FEATDN))[n] = make_float4(f1, f2, f3, vn);

    int pos = atomicAdd((int*)(ws + OFF_BFIL) + bin9(v.x), 1);
    ((float4*)(ws + OFF_P4S))[pos] = make_float4(v.x, v.y, v.z, __int_as_float(n));
}

// ---------------- ysort: counting-sort each 1024-window by y (intra-bin order arbitrary) ----------------
__global__ __launch_bounds__(256) void ysort_kernel(float* __restrict__ ws)
{
    __shared__ int cnt[64], ofs[64];
    const int w = blockIdx.x, tid = threadIdx.x;
    float4* p = (float4*)(ws + OFF_P4S);
    if (tid < 64) cnt[tid] = 0;
    __syncthreads();
    float4 v[4]; int b[4];
    #pragma unroll
    for (int i = 0; i < 4; ++i) {
        v[i] = p[w*1024 + tid + i*256];
        b[i] = bin9(v[i].y);
        atomicAdd(&cnt[b[i]], 1);
    }
    __syncthreads();
    if (tid == 0) { int a = 0; for (int i = 0; i < 64; ++i) { ofs[i] = a; a += cnt[i]; } }
    __syncthreads();
    #pragma unroll
    for (int i = 0; i < 4; ++i) {
        int pos = atomicAdd(&ofs[b[i]], 1);
        p[w*1024 + pos] = v[i];
    }
}

// ---------------- bounds: per-window x bounds + per-64-subtile y bounds ----------------
__global__ __launch_bounds__(256) void bounds_kernel(float* __restrict__ ws)
{
    const int w = blockIdx.x, tid = threadIdx.x;
    const float4* p = (const float4*)(ws + OFF_P4S);
    float ymn = 1e30f, ymx = -1e30f, xmn = 1e30f, xmx = -1e30f;
    #pragma unroll
    for (int i = 0; i < 4; ++i) {
        float4 v = p[w*1024 + tid*4 + i];
        ymn = fminf(ymn, v.y); ymx = fmaxf(ymx, v.y);
        xmn = fminf(xmn, v.x); xmx = fmaxf(xmx, v.x);
    }
    // subtile (64 pts) = 16 consecutive threads
    for (int j = 1; j < 16; j <<= 1) {
        ymn = fminf(ymn, __shfl_xor(ymn, j));
        ymx = fmaxf(ymx, __shfl_xor(ymx, j));
    }
    if ((tid & 15) == 0) {
        int sub = tid >> 4;   // 0..15
        ws[OFF_SBND + w*32 + 2*sub]     = ymn;
        ws[OFF_SBND + w*32 + 2*sub + 1] = ymx;
    }
    for (int j = 1; j < 64; j <<= 1) {
        xmn = fminf(xmn, __shfl_xor(xmn, j));
        xmx = fmaxf(xmx, __shfl_xor(xmx, j));
    }
    __shared__ float sxn[4], sxx[4];
    if ((tid & 63) == 0) { sxn[tid >> 6] = xmn; sxx[tid >> 6] = xmx; }
    __syncthreads();
    if (tid == 0) {
        float MN = fminf(fminf(sxn[0], sxn[1]), fminf(sxn[2], sxn[3]));
        float MX = fmaxf(fmaxf(sxx[0], sxx[1]), fmaxf(sxx[2], sxx[3]));
        ws[OFF_TBND + 2*w] = MN;
        ws[OFF_TBND + 2*w + 1] = MX;
    }
}

// ---------------- weight prep: zeros, wt1 transpose, bf16 conv+MLP weights ----------------
__global__ __launch_bounds__(256) void wt_kernel(
    const float* __restrict__ c1w, const float* __restrict__ c2w,
    const float* __restrict__ c3w, const float* __restrict__ c4w,
    const float* __restrict__ gw0, const float* __restrict__ gw1,
    const float* __restrict__ gw2, const float* __restrict__ gw3,
    const float* __restrict__ gw4,
    float* __restrict__ ws)
{
    const int t = blockIdx.x * 256 + threadIdx.x;
    const int T = gridDim.x * 256;
    for (int m = t; m < 2944; m += T) ws[OFF_STATS + m] = 0.f;
    for (int m = t; m < 64; m += T) ((int*)(ws + OFF_BCNT))[m] = 0;
    for (int m = t; m < 64*4; m += T) { int o = m >> 2, c = m & 3; ws[OFF_WT1 + c*64 + o] = c1w[m]; }

    unsigned short* bw2 = (unsigned short*)(ws + OFF_BW2);
    for (int m = t; m < 128*64; m += T)   bw2[m] = f2bf(c2w[m]);
    unsigned short* bw3 = (unsigned short*)(ws + OFF_BW3);
    for (int m = t; m < 256*192; m += T)  bw3[m] = f2bf(c3w[m]);
    unsigned short* bw4 = (unsigned short*)(ws + OFF_BW4);
    for (int m = t; m < 1024*256; m += T) bw4[m] = f2bf(c4w[m]);

    unsigned short* gwt = (unsigned short*)(ws + OFF_GWT);
    for (int m = t; m < 2048; m += T) {          // gw0T padded [64][32]
        int o = m >> 5, i = m & 31;
        gwt[m] = (i < 4) ? f2bf(gw0[i*64 + o]) : (unsigned short)0;
    }
    const float* gsrc[4] = {gw1, gw2, gw3, gw4};
    for (int l = 0; l < 4; ++l) {
        const float* g = gsrc[l];
        unsigned short* dst = gwt + 2048 + l*4096;
        for (int m = t; m < 4096; m += T) { int o = m >> 6, i = m & 63; dst[m] = f2bf(g[i*64 + o]); }
    }
}

// ---------------- KNN v6: v5 + y-sorted subtiles (2-D pruning) ----------------
// 1024 blocks x 256 threads (4 waves); block owns 8 consecutive slots of the
// (x-window, y-within-window)-sorted order; wave handles 2 adjacent queries.
// Window sweep center-out in x with block votes (v5). Inside a window, each
// wave skips 64-pt subtiles via gapx_window^2 + gapy_subtile^2 > kthd (valid
// lower bound; `continue` not `break` since counting-sort y-bounds are only
// approximately monotone). Enqueue d<=kthd; u64 (dist,origIdx) keys keep the
// selection exact under any scan order.
__global__ __launch_bounds__(256) void knn_feat_kernel(
    const float4* __restrict__ p4,       // original order (feature phase)
    const float4* __restrict__ p4s,      // sorted; w = as_float(origIdx)
    const float* __restrict__ wbnd,      // [8][2] window xmin,xmax
    const float* __restrict__ sbnd,      // [128][2] subtile ymin,ymax
    uint2* __restrict__ feat_up)         // packed bf16 (f1,f2 | f3,vn)
{
    __shared__ __align__(16) float4 stage[1024];                 // 16 KB
    __shared__ unsigned long long queue[4][2][128];              // 8 KB
    __shared__ float sb[16], sy[256], pmx[8], pmn[8];
    __shared__ int voteL, voteR, nextT;

    const int lane = threadIdx.x & 63;
    const int wid  = threadIdx.x >> 6;
    for (int i = threadIdx.x; i < 16; i += 256) sb[i] = wbnd[i];
    for (int i = threadIdx.x; i < 256; i += 256) sy[i] = sbnd[i];
    __syncthreads();
    if (threadIdx.x == 0) {
        float m = -1e30f;
        for (int w = 0; w < 8; ++w) { m = fmaxf(m, sb[2*w+1]); pmx[w] = m; }
        float n = 1e30f;
        for (int w = 7; w >= 0; --w) { n = fminf(n, sb[2*w]); pmn[w] = n; }
    }

    const int s0 = blockIdx.x * 8 + wid * 2;
    float4 qa = p4s[s0];
    float4 qb = p4s[s0 + 1];
    const int qi0 = __float_as_int(qa.w), qi1 = __float_as_int(qb.w);
    qa.w = fmaf(qa.x, qa.x, fmaf(qa.y, qa.y, qa.z * qa.z));
    qb.w = fmaf(qb.x, qb.x, fmaf(qb.y, qb.y, qb.z * qb.z));

    unsigned long long* Q0 = queue[wid][0];
    unsigned long long* Q1 = queue[wid][1];
    unsigned long long cur0 = ~0ull, cur1 = ~0ull;
    float kthd0 = __builtin_inff(), kthd1 = __builtin_inff();
    int qc0 = 0, qc1 = 0;

    const int w0 = blockIdx.x >> 7;      // 1024 blocks / 8 windows
    int L = w0, R = w0, t = w0;

    for (;;) {
        __syncthreads();
        for (int i = threadIdx.x; i < 1024; i += 256) stage[i] = p4s[t*1024 + i];
        if (threadIdx.x == 0) { voteL = 0; voteR = 0; }
        __syncthreads();

        float wmn = sb[2*t], wmx = sb[2*t+1];
        float ga = fmaxf(fmaxf(qa.x - wmx, wmn - qa.x), 0.f);
        float gb = fmaxf(fmaxf(qb.x - wmx, wmn - qb.x), 0.f);
        float ga2 = ga*ga, gb2 = gb*gb;
        if (!((ga2 > kthd0) && (gb2 > kthd1))) {
            #pragma unroll 1
            for (int sub = 0; sub < 16; ++sub) {
                float smn = sy[t*32 + 2*sub], smx = sy[t*32 + 2*sub + 1];
                float gya = fmaxf(fmaxf(qa.y - smx, smn - qa.y), 0.f);
                float gyb = fmaxf(fmaxf(qb.y - smx, smn - qb.y), 0.f);
                if ((fmaf(gya, gya, ga2) > kthd0) && (fmaf(gyb, gyb, gb2) > kthd1)) continue;

                float4 cd = stage[sub*64 + lane];
                int ci = __float_as_int(cd.w);
                float cr = fmaf(cd.x, cd.x, fmaf(cd.y, cd.y, cd.z * cd.z));
                float dot0 = fmaf(qa.x, cd.x, fmaf(qa.y, cd.y, qa.z * cd.z));
                float d0   = fmaf(-2.f, dot0, qa.w) + cr;
                float dot1 = fmaf(qb.x, cd.x, fmaf(qb.y, cd.y, qb.z * cd.z));
                float d1   = fmaf(-2.f, dot1, qb.w) + cr;
                bool p0 = d0 <= kthd0, p1 = d1 <= kthd1;
                unsigned long long m0 = __ballot(p0);
                unsigned long long m1 = __ballot(p1);
                if (m0) {
                    int prefix = __builtin_amdgcn_mbcnt_hi((unsigned)(m0 >> 32),
                                  __builtin_amdgcn_mbcnt_lo((unsigned)m0, 0));
                    if (p0) Q0[qc0 + prefix] = ((unsigned long long)f2u(d0) << 32)
                                             | (unsigned long long)(unsigned)ci;
                    qc0 += __popcll(m0);
                    if (qc0 >= 64) {
                        qc0 -= 64;
                        cur0 = sort_merge(Q0[qc0 + lane], cur0, lane);
                        kthd0 = key_to_f(__shfl(cur0, 63));
                    }
                }
                if (m1) {
                    int prefix = __builtin_amdgcn_mbcnt_hi((unsigned)(m1 >> 32),
                                  __builtin_amdgcn_mbcnt_lo((unsigned)m1, 0));
                    if (p1) Q1[qc1 + prefix] = ((unsigned long long)f2u(d1) << 32)
                                             | (unsigned long long)(unsigned)ci;
                    qc1 += __popcll(m1);
                    if (qc1 >= 64) {
                        qc1 -= 64;
                        cur1 = sort_merge(Q1[qc1 + lane], cur1, lane);
                        kthd1 = key_to_f(__shfl(cur1, 63));
                    }
                }
            }
        }

        if (lane == 0) {
            bool needL = false, needR = false;
            if (L > 0) {
                float p = pmx[L-1];
                float g0 = qa.x - p, g1 = qb.x - p;
                bool st0 = (g0 > 0.f) && (g0*g0 > kthd0);
                bool st1 = (g1 > 0.f) && (g1*g1 > kthd1);
                needL = !(st0 && st1);
            }
            if (R < 7) {
                float p = pmn[R+1];
                float g0 = p - qa.x, g1 = p - qb.x;
                bool st0 = (g0 > 0.f) && (g0*g0 > kthd0);
                bool st1 = (g1 > 0.f) && (g1*g1 > kthd1);
                needR = !(st0 && st1);
            }
            if (needL) atomicOr(&voteL, 1);
            if (needR) atomicOr(&voteR, 1);
        }
        __syncthreads();
        if (threadIdx.x == 0) {
            bool cL = (voteL != 0) && (L > 0);
            bool cR = (voteR != 0) && (R < 7);
            int nt = -1;
            if (cL && cR) nt = ((w0 - (L-1)) <= ((R+1) - w0)) ? (L-1) : (R+1);
            else if (cL) nt = L - 1;
            else if (cR) nt = R + 1;
            nextT = nt;
        }
        __syncthreads();
        t = nextT;
        if (t < 0) break;
        if (t < L) L = t; else R = t;
    }

    cur0 = sort_merge((lane < qc0) ? Q0[lane] : ~0ull, cur0, lane);
    cur1 = sort_merge((lane < qc1) ? Q1[lane] : ~0ull, cur1, lane);

    // features; lane k = k-th nearest (asc distance, idx tie-break)
    #pragma unroll 1
    for (int j = 0; j < 2; ++j) {
        unsigned long long cur = j ? cur1 : cur0;
        const int q = j ? qi1 : qi0;
        int nidx = (int)(unsigned)(cur & 0xFFFFFFFFu);
        float4 np = p4[nidx];
        float ox = __shfl(np.x, 0), oy = __shfl(np.y, 0), oz = __shfl(np.z, 0);
        float pcx = np.x - ox, pcy = np.y - oy, pcz = np.z - oz;
        float vn = sqrtf(pcx*pcx + pcy*pcy + pcz*pcz);

        unsigned long long ak = ((unsigned long long)__float_as_uint(vn) << 32)
                              | (unsigned long long)(unsigned)(63 - lane);
        for (int s = 32; s > 0; s >>= 1) ak = u64max(ak, __shfl_xor(ak, s));
        int id1 = 63 - (int)(unsigned)(ak & 0xFFFFFFFFu);

        float a1x = __shfl(pcx, id1), a1y = __shfl(pcy, id1), a1z = __shfl(pcz, id1);
        float n1 = sqrtf(a1x*a1x + a1y*a1y + a1z*a1z) + EPSF;
        a1x /= n1; a1y /= n1; a1z /= n1;

        float sx = pcx, sy2 = pcy, sz = pcz;
        for (int s = 32; s > 0; s >>= 1) {
            sx += __shfl_xor(sx, s); sy2 += __shfl_xor(sy2, s); sz += __shfl_xor(sz, s);
        }
        float a2x = sx * (1.f/64.f), a2y = sy2 * (1.f/64.f), a2z = sz * (1.f/64.f);
        float n2 = sqrtf(a2x*a2x + a2y*a2y + a2z*a2z) + EPSF;
        a2x /= n2; a2y /= n2; a2z /= n2;

        float a3x = a1x + 1.5f*a2x, a3y = a1y + 1.5f*a2y, a3z = a1z + 1.5f*a2z;
        float n3 = sqrtf(a3x*a3x + a3y*a3y + a3z*a3z) + EPSF;
        a3x /= n3; a3y /= n3; a3z /= n3;

        float den = vn + EPSF;
        float f1 = (pcx*a1x + pcy*a1y + pcz*a1z) / den;
        float f2 = (pcx*a2x + pcy*a2y + pcz*a2z) / den;
        float f3 = (pcx*a3x + pcy*a3y + pcz*a3z) / den;
        uint2 pk;
        pk.x = (unsigned)f2bf(f1) | ((unsigned)f2bf(f2) << 16);
        pk.y = (unsigned)f2bf(f3) | ((unsigned)f2bf(vn) << 16);
        feat_up[q*64 + lane] = pk;
    }
}

// ---------------- 5-layer MLP via bf16 MFMA + max over K ----------------
// feat_up is packed bf16 (uint2). Epilogue writes emb_up's RAW-RESHAPE view
// into conv3's B operand: (point q, feature f) -> xb3[((q&127)*64+f)*192 + (q>>7)].
#define BROW 72
__global__ __launch_bounds__(256) void mlp_kernel(
    const uint2* __restrict__ feat_up,
    const unsigned short* __restrict__ gwt,
    unsigned short* __restrict__ xb3)
{
    __shared__ __align__(16) unsigned short Blds[4][64 * BROW];
    const int lane = threadIdx.x & 63;
    const int wid  = threadIdx.x >> 6;
    const int q = blockIdx.x * 4 + wid;
    const int c = lane & 15, g = lane >> 4;
    unsigned short* B = Blds[wid];

    {
        uint2 p0 = feat_up[q*64 + lane];
        *(uint2*)&B[lane*BROW] = p0;
        *(uint2*)&B[lane*BROW + 4] = make_uint2(0, 0);
        uint4 z4 = make_uint4(0, 0, 0, 0);
        *(uint4*)&B[lane*BROW + 8]  = z4;
        *(uint4*)&B[lane*BROW + 16] = z4;
        *(uint4*)&B[lane*BROW + 24] = z4;
    }

    const unsigned short* Wl[5] = {gwt, gwt + 2048, gwt + 6144, gwt + 10240, gwt + 14336};
    f32x4 acc[4][4];

    for (int layer = 0; layer < 5; ++layer) {
        const int wstride = (layer == 0) ? 32 : 64;
        const int nks = (layer == 0) ? 1 : 2;
        #pragma unroll
        for (int mb = 0; mb < 4; ++mb)
            #pragma unroll
            for (int nb = 0; nb < 4; ++nb)
                acc[mb][nb] = (f32x4){0.f, 0.f, 0.f, 0.f};

        for (int ks = 0; ks < nks; ++ks) {
            bf16x8 af[4], bf[4];
            #pragma unroll
            for (int mb = 0; mb < 4; ++mb)
                af[mb] = *(const bf16x8*)(Wl[layer] + (mb*16 + c)*wstride + ks*32 + g*8);
            #pragma unroll
            for (int nb = 0; nb < 4; ++nb)
                bf[nb] = *(const bf16x8*)&B[(nb*16 + c)*BROW + ks*32 + g*8];
            #pragma unroll
            for (int mb = 0; mb < 4; ++mb)
                #pragma unroll
                for (int nb = 0; nb < 4; ++nb)
                    acc[mb][nb] = __builtin_amdgcn_mfma_f32_16x16x32_bf16(af[mb], bf[nb], acc[mb][nb], 0, 0, 0);
        }

        if (layer < 4) {
            #pragma unroll
            for (int mb = 0; mb < 4; ++mb) {
                #pragma unroll
                for (int nb = 0; nb < 4; ++nb) {
                    f32x4 a = acc[mb][nb];
                    float r0 = fmaxf(a[0], 0.f), r1 = fmaxf(a[1], 0.f);
                    float r2 = fmaxf(a[2], 0.f), r3 = fmaxf(a[3], 0.f);
                    uint2 pw;
                    pw.x = (unsigned)f2bf(r0) | ((unsigned)f2bf(r1) << 16);
                    pw.y = (unsigned)f2bf(r2) | ((unsigned)f2bf(r3) << 16);
                    *(uint2*)&B[(nb*16 + c)*BROW + mb*16 + g*4] = pw;
                }
            }
        }
    }

    const int cc = q >> 7;
    const int pbase = (q & 127) << 6;
    #pragma unroll
    for (int mb = 0; mb < 4; ++mb) {
        float v[4];
        #pragma unroll
        for (int r = 0; r < 4; ++r)
            v[r] = fmaxf(fmaxf(fmaxf(acc[mb][0][r], acc[mb][1][r]),
                               fmaxf(acc[mb][2][r], acc[mb][3][r])), 0.f);
        #pragma unroll
        for (int mask = 1; mask <= 8; mask <<= 1)
            #pragma unroll
            for (int r = 0; r < 4; ++r)
                v[r] = fmaxf(v[r], __shfl_xor(v[r], mask));
        if (c == 0) {
            #pragma unroll
            for (int r = 0; r < 4; ++r) {
                const int f = mb*16 + g*4 + r;
                xb3[(size_t)(pbase + f) * 192 + cc] = f2bf(v[r]);
            }
        }
    }
}

// ---------------- conv1 (fp32 GEMV, K=4) with output stats ----------------
__global__ __launch_bounds__(256) void conv1_kernel(
    const float* __restrict__ x, const float* __restrict__ wt,
    const float* __restrict__ bias, float* __restrict__ y,
    float* __restrict__ stout)
{
    const int tid = threadIdx.x;
    const int p  = blockIdx.x * 256 + tid;
    const int o0 = blockIdx.y * 32;
    float acc[32];
    #pragma unroll
    for (int u = 0; u < 32; ++u) acc[u] = bias[o0 + u];
    #pragma unroll
    for (int c = 0; c < 4; ++c) {
        float xv = x[c * NPTS + p];
        const float* wr = wt + c * 64 + o0;
        #pragma unroll
        for (int u = 0; u < 32; ++u) acc[u] = fmaf(xv, wr[u], acc[u]);
    }
    #pragma unroll
    for (int u = 0; u < 32; ++u) y[(o0 + u) * NPTS + p] = acc[u];

    __shared__ float ps[4][32], pss[4][32];
    const int wid = tid >> 6, lane = tid & 63;
    #pragma unroll
    for (int u = 0; u < 32; ++u) {
        float s = acc[u], ss = acc[u] * acc[u];
        for (int j = 32; j > 0; j >>= 1) { s += __shfl_xor(s, j); ss += __shfl_xor(ss, j); }
        if (lane == 0) { ps[wid][u] = s; pss[wid][u] = ss; }
    }
    __syncthreads();
    if (tid < 32) {
        float S  = ps[0][tid] + ps[1][tid] + ps[2][tid] + ps[3][tid];
        float SS = pss[0][tid] + pss[1][tid] + pss[2][tid] + pss[3][tid];
        atomicAdd(&stout[o0 + tid], S);
        atomicAdd(&stout[64 + o0 + tid], SS);
    }
}

// ---------------- bnpack: y fp32 [C][N] -> BN+ReLU -> bf16 xb[p][stride] at col offset ----------------
__global__ __launch_bounds__(256) void bnpack_kernel(
    const float* __restrict__ y, const float* __restrict__ st,
    const float* __restrict__ gam, const float* __restrict__ bet,
    int C, int stride, int coff, unsigned short* __restrict__ xb)
{
    __shared__ float sc[256], sh[256];
    __shared__ __align__(16) unsigned short tile[64][264];
    const int tid = threadIdx.x;
    for (int cc = tid; cc < C; cc += 256) {
        float mu  = st[cc] * (1.f / 8192.f);
        float var = st[C + cc] * (1.f / 8192.f) - mu * mu;
        float s = gam[cc] / sqrtf(var + 1e-5f);
        sc[cc] = s; sh[cc] = bet[cc] - mu * s;
    }
    __syncthreads();
    const int pl = tid & 63, g = tid >> 6;
    const int p = blockIdx.x * 64 + pl;
    for (int c0 = g * 8; c0 < C; c0 += 32) {
        unsigned pk[4];
        #pragma unroll
        for (int h = 0; h < 4; ++h) {
            float v0 = fmaxf(fmaf(y[(c0 + 2*h    ) * NPTS + p], sc[c0 + 2*h    ], sh[c0 + 2*h    ]), 0.f);
            float v1 = fmaxf(fmaf(y[(c0 + 2*h + 1) * NPTS + p], sc[c0 + 2*h + 1], sh[c0 + 2*h + 1]), 0.f);
            pk[h] = (unsigned)f2bf(v0) | ((unsigned)f2bf(v1) << 16);
        }
        *(uint4*)&tile[pl][c0] = make_uint4(pk[0], pk[1], pk[2], pk[3]);
    }
    __syncthreads();
    const int cpr = C >> 3;
    const int nch = 64 * cpr;
    for (int idx = tid; idx < nch; idx += 256) {
        int r = idx / cpr, cc = (idx - r * cpr) * 8;
        *(uint4*)&xb[(size_t)(blockIdx.x * 64 + r) * stride + coff + cc] = *(uint4*)&tile[r][cc];
    }
}

// ---------------- conv via MFMA: y[M][N] = A[M][K](bf16) x Xb[N][K](bf16)^T + bias ----------------
__global__ __launch_bounds__(256) void conv_mfma_kernel(
    const unsigned short* __restrict__ A, const unsigned short* __restrict__ Bx,
    const float* __restrict__ bias, int K, int M,
    float* __restrict__ y, float* __restrict__ stout)
{
    const int lane = threadIdx.x & 63;
    const int w = threadIdx.x >> 6;
    const int n0 = blockIdx.x * 256 + w * 64;
    const int m0 = blockIdx.y * 64;
    const int c = lane & 15, g = lane >> 4;

    f32x4 acc[4][4];
    #pragma unroll
    for (int mt = 0; mt < 4; ++mt)
        #pragma unroll
        for (int nt = 0; nt < 4; ++nt)
            acc[mt][nt] = (f32x4){0.f, 0.f, 0.f, 0.f};

    for (int k0 = 0; k0 < K; k0 += 32) {
        bf16x8 af[4], bf[4];
        #pragma unroll
        for (int mt = 0; mt < 4; ++mt)
            af[mt] = *(const bf16x8*)(A + (size_t)(m0 + mt*16 + c) * K + k0 + g*8);
        #pragma unroll
        for (int nt = 0; nt < 4; ++nt)
            bf[nt] = *(const bf16x8*)(Bx + (size_t)(n0 + nt*16 + c) * K + k0 + g*8);
        #pragma unroll
        for (int mt = 0; mt < 4; ++mt)
            #pragma unroll
            for (int nt = 0; nt < 4; ++nt)
                acc[mt][nt] = __builtin_amdgcn_mfma_f32_16x16x32_bf16(af[mt], bf[nt], acc[mt][nt], 0, 0, 0);
    }

    #pragma unroll
    for (int mt = 0; mt < 4; ++mt) {
        float s[4], ss[4];
        #pragma unroll
        for (int r = 0; r < 4; ++r) {
            const int o = m0 + mt*16 + g*4 + r;
            const float bv = bias[o];
            float sum = 0.f, sq = 0.f;
            #pragma unroll
            for (int nt = 0; nt < 4; ++nt) {
                float v = acc[mt][nt][r] + bv;
                y[(size_t)o * NPTS + n0 + nt*16 + c] = v;
                sum += v; sq += v * v;
            }
            s[r] = sum; ss[r] = sq;
        }
        #pragma unroll
        for (int mask = 1; mask <= 8; mask <<= 1)
            #pragma unroll
            for (int r = 0; r < 4; ++r) {
                s[r]  += __shfl_xor(s[r],  mask);
                ss[r] += __shfl_xor(ss[r], mask);
            }
        if (c == 0) {
            #pragma unroll
            for (int r = 0; r < 4; ++r) {
                const int o = m0 + mt*16 + g*4 + r;
                atomicAdd(&stout[o], s[r]);
                atomicAdd(&stout[M + o], ss[r]);
            }
        }
    }
}

// ---------------- final BN + ReLU (in place on d_out) ----------------
__global__ __launch_bounds__(256) void bnrelu_kernel(
    const float* y, const float* __restrict__ st,
    const float* __restrict__ g, const float* __restrict__ b,
    float* out, int C)
{
    int idx = blockIdx.x * 256 + threadIdx.x;
    int c = idx >> 13;   // N = 8192
    float mu  = st[c] * (1.f / 8192.f);
    float var = st[C + c] * (1.f / 8192.f) - mu * mu;
    float scale = g[c] / sqrtf(var + 1e-5f);
    float v = fmaf(y[idx] - mu, scale, b[c]);
    out[idx] = fmaxf(v, 0.f);
}

extern "C" void kernel_launch(void* const* d_in, const int* in_sizes, int n_in,
                              void* d_out, int out_size, void* d_ws, size_t ws_size,
                              hipStream_t stream) {
    const float* points = (const float*)d_in[0];
    const float* gw0 = (const float*)d_in[1];
    const float* gw1 = (const float*)d_in[2];
    const float* gw2 = (const float*)d_in[3];
    const float* gw3 = (const float*)d_in[4];
    const float* gw4 = (const float*)d_in[5];
    const float* c1w = (const float*)d_in[6];  const float* c1b = (const float*)d_in[7];
    const float* bn1g = (const float*)d_in[8]; const float* bn1b = (const float*)d_in[9];
    const float* c2w = (const float*)d_in[10]; const float* c2b = (const float*)d_in[11];
    const float* bn2g = (const float*)d_in[12];const float* bn2b = (const float*)d_in[13];
    const float* c3w = (const float*)d_in[14]; const float* c3b = (const float*)d_in[15];
    const float* bn3g = (const float*)d_in[16];const float* bn3b = (const float*)d_in[17];
    const float* c4w = (const float*)d_in[18]; const float* c4b = (const float*)d_in[19];
    const float* bn4g = (const float*)d_in[20];const float* bn4b = (const float*)d_in[21];

    float* ws = (float*)d_ws;
    float* featdn = ws + OFF_FEATDN;
    float* y1 = ws + OFF_Y1; float* y2 = ws + OFF_Y2; float* y3 = ws + OFF_Y3;
    float* s1 = ws + OFF_STATS + 0;
    float* s2 = ws + OFF_STATS + 128;
    float* s3 = ws + OFF_STATS + 384;
    float* s4 = ws + OFF_STATS + 896;
    float* wt1 = ws + OFF_WT1;
    const unsigned short* gwt = (const unsigned short*)(ws + OFF_GWT);
    const unsigned short* bw2 = (const unsigned short*)(ws + OFF_BW2);
    const unsigned short* bw3 = (const unsigned short*)(ws + OFF_BW3);
    const unsigned short* bw4 = (const unsigned short*)(ws + OFF_BW4);
    unsigned short* xb1 = (unsigned short*)(ws + OFF_XB1);
    unsigned short* xb3 = (unsigned short*)(ws + OFF_XB3);
    unsigned short* xb4 = (unsigned short*)(ws + OFF_XB4);
    uint2* featup = (uint2*)(ws + OFF_FEATUP);
    float* outp = (float*)d_out;

    wt_kernel<<<256, 256, 0, stream>>>(c1w, c2w, c3w, c4w, gw0, gw1, gw2, gw3, gw4, ws);
    prep_a_kernel<<<32, 256, 0, stream>>>(points, ws);
    prep_b_kernel<<<1, 64, 0, stream>>>(points, ws);
    prep_cs_kernel<<<32, 256, 0, stream>>>(ws);
    ysort_kernel<<<8, 256, 0, stream>>>(ws);
    bounds_kernel<<<8, 256, 0, stream>>>(ws);

    knn_feat_kernel<<<1024, 256, 0, stream>>>(
        (const float4*)(ws + OFF_P4), (const float4*)(ws + OFF_P4S),
        ws + OFF_TBND, ws + OFF_SBND, featup);
    mlp_kernel<<<2048, 256, 0, stream>>>(featup, gwt, xb3);

    conv1_kernel<<<dim3(32, 2), 256, 0, stream>>>(featdn, wt1, c1b, y1, s1);
    bnpack_kernel<<<128, 256, 0, stream>>>(y1, s1, bn1g, bn1b, 64, 64, 0, xb1);
    conv_mfma_kernel<<<dim3(32, 2), 256, 0, stream>>>(bw2, xb1, c2b, 64, 128, y2, s2);
    bnpack_kernel<<<128, 256, 0, stream>>>(y2, s2, bn2g, bn2b, 128, 192, 64, xb3);
    conv_mfma_kernel<<<dim3(32, 4), 256, 0, stream>>>(bw3, xb3, c3b, 192, 256, y3, s3);
    bnpack_kernel<<<128, 256, 0, stream>>>(y3, s3, bn3g, bn3b, 256, 256, 0, xb4);
    conv_mfma_kernel<<<dim3(32, 16), 256, 0, stream>>>(bw4, xb4, c4b, 256, 1024, outp, s4);
    bnrelu_kernel<<<1024*32, 256, 0, stream>>>(outp, s4, bn4g, bn4b, outp, 1024);
}

// Round 11
// 392.867 us; speedup vs baseline: 1.1236x; 1.1236x over previous
//
#include <hip/hip_runtime.h>
#include <hip/hip_bf16.h>

#define NPTS 8192
#define KNN 64
#define EPSF 1e-7f

// ---------------- workspace layout (float offsets) ----------------
#define OFF_P4      0              // packed (x,y,z,rr) float4 per point: 4*N
#define OFF_STATS   32768          // s1:+0(128) s2:+128(256) s3:+384(512) s4:+896(2048) = 2944
#define OFF_AVEC    36000          // 9 floats a1,a2,a3
#define OFF_PART    36012          // 32 blocks x 2 u64 = 128 floats
#define OFF_FEATDN  36864          // N*4 -> 69632
#define OFF_WT1     69632          // 4*64 fp32 transposed -> 69888
#define OFF_GWT     69888          // MLP bf16 weights
#define OFF_BW2     79104          // c2w bf16
#define OFF_BW3     83200          // c3w bf16
#define OFF_BW4     107776         // c4w bf16
#define OFF_XB1     238848         // bf16 [8192][64]
#define OFF_XB3     500992         // bf16 [8192][192]
#define OFF_XB4     1287424        // bf16 [8192][256]
#define OFF_Y1      2336000        // 64*N fp32 (hosts KNN-phase scratch before conv1)
#define OFF_Y2      2860288        // 128*N fp32
#define OFF_Y3      3908864        // 256*N fp32
#define OFF_FEATUP  6006016        // N*K uint2 (packed bf16 feats)

// KNN-phase scratch parked inside Y1 (dead until conv1 runs, after knn completes)
#define OFF_P4S     OFF_Y1             // x-sorted packed points, w = as_float(origIdx): 32768 floats
#define OFF_TBND    (OFF_Y1 + 32768)   // per-window [xmin,xmax]: 16 floats (8 windows of 1024)
#define OFF_BCNT    (OFF_Y1 + 33024)   // 64 bin counts (int)
#define OFF_BOFS    (OFF_Y1 + 33088)   // 65 bin offsets (int)
#define OFF_BFIL    (OFF_Y1 + 33156)   // 64 bin fill cursors (int)

typedef __bf16 bf16x8 __attribute__((ext_vector_type(8)));
typedef float  f32x4  __attribute__((ext_vector_type(4)));

__device__ __forceinline__ unsigned f2u(float f) {
    unsigned u = __float_as_uint(f);
    return ((int)u >= 0) ? (u | 0x80000000u) : ~u;
}
__device__ __forceinline__ float key_to_f(unsigned long long k) {
    unsigned v = (unsigned)(k >> 32);
    unsigned ob = (v & 0x80000000u) ? (v ^ 0x80000000u) : ~v;
    return __uint_as_float(ob);
}
__device__ __forceinline__ unsigned short f2bf(float x) {
    unsigned u = __float_as_uint(x);
    unsigned r = (u + 0x7FFFu + ((u >> 16) & 1u)) >> 16;   // RNE
    return (unsigned short)r;
}
__device__ __forceinline__ unsigned long long u64min(unsigned long long a, unsigned long long b){ return a < b ? a : b; }
__device__ __forceinline__ unsigned long long u64max(unsigned long long a, unsigned long long b){ return a < b ? b : a; }

__device__ __forceinline__ unsigned long long sort_merge(
    unsigned long long key, unsigned long long cur, int lane)
{
    #pragma unroll
    for (int k = 2; k <= 64; k <<= 1) {
        #pragma unroll
        for (int j = k >> 1; j > 0; j >>= 1) {
            unsigned long long o = __shfl_xor(key, j);
            bool up = ((lane & k) == 0);
            bool lower = ((lane & j) == 0);
            key = (lower == up) ? u64min(key, o) : u64max(key, o);
        }
    }
    unsigned long long rev = __shfl(key, 63 - lane);
    unsigned long long m = u64min(cur, rev);
    #pragma unroll
    for (int j = 32; j > 0; j >>= 1) {
        unsigned long long o = __shfl_xor(m, j);
        m = ((lane & j) == 0) ? u64min(m, o) : u64max(m, o);
    }
    return m;
}

__device__ __forceinline__ int bin9(float x) {
    int b = (int)((x + 4.5f) * (64.0f / 9.0f));
    return min(63, max(0, b));
}

// ---------------- prep A: p4, x-histogram, argmax/argmin partials ----------------
__global__ __launch_bounds__(256) void prep_a_kernel(
    const float* __restrict__ points, float* __restrict__ ws)
{
    const int n = blockIdx.x * 256 + threadIdx.x;
    float x = points[3*n+0], y = points[3*n+1], z = points[3*n+2];
    float rr = x*x + y*y + z*z;
    ((float4*)(ws + OFF_P4))[n] = make_float4(x, y, z, rr);
    atomicAdd((int*)(ws + OFF_BCNT) + bin9(x), 1);
    float vn = sqrtf(rr);
    unsigned b = __float_as_uint(vn);
    unsigned long long mxk = ((unsigned long long)b << 32) | (unsigned long long)(0xFFFFFFFFu - (unsigned)n);
    unsigned long long mnk = ((unsigned long long)b << 32) | (unsigned long long)(unsigned)n;
    for (int j = 32; j > 0; j >>= 1) {
        mxk = u64max(mxk, __shfl_xor(mxk, j));
        mnk = u64min(mnk, __shfl_xor(mnk, j));
    }
    __shared__ unsigned long long smx[4], smn[4];
    int wid = threadIdx.x >> 6;
    if ((threadIdx.x & 63) == 0) { smx[wid] = mxk; smn[wid] = mnk; }
    __syncthreads();
    if (threadIdx.x == 0) {
        unsigned long long MX = 0ull, MN = ~0ull;
        for (int i = 0; i < 4; ++i) { MX = u64max(MX, smx[i]); MN = u64min(MN, smn[i]); }
        unsigned long long* parts = (unsigned long long*)(ws + OFF_PART);
        parts[2*blockIdx.x + 0] = MX;
        parts[2*blockIdx.x + 1] = MN;
    }
}

// ---------------- prep B: reduce partials -> a1/a2/a3; bin prefix sums ----------------
__global__ __launch_bounds__(64) void prep_b_kernel(
    const float* __restrict__ points, float* __restrict__ ws)
{
    const int lane = threadIdx.x;
    const unsigned long long* parts = (const unsigned long long*)(ws + OFF_PART);
    unsigned long long mxk = (lane < 32) ? parts[2*lane + 0] : 0ull;
    unsigned long long mnk = (lane < 32) ? parts[2*lane + 1] : ~0ull;
    for (int j = 32; j > 0; j >>= 1) {
        mxk = u64max(mxk, __shfl_xor(mxk, j));
        mnk = u64min(mnk, __shfl_xor(mnk, j));
    }
    if (lane == 0) {
        int i1 = (int)(0xFFFFFFFFu - (unsigned)(mxk & 0xFFFFFFFFu));
        int i2 = (int)(unsigned)(mnk & 0xFFFFFFFFu);
        float a1x = points[3*i1+0], a1y = points[3*i1+1], a1z = points[3*i1+2];
        float n1 = sqrtf(a1x*a1x + a1y*a1y + a1z*a1z) + EPSF;
        a1x /= n1; a1y /= n1; a1z /= n1;
        float a2x = points[3*i2+0], a2y = points[3*i2+1], a2z = points[3*i2+2];
        float n2 = sqrtf(a2x*a2x + a2y*a2y + a2z*a2z) + EPSF;
        a2x /= n2; a2y /= n2; a2z /= n2;
        float a3x = a1x + 1.5f*a2x, a3y = a1y + 1.5f*a2y, a3z = a1z + 1.5f*a2z;
        float n3 = sqrtf(a3x*a3x + a3y*a3y + a3z*a3z) + EPSF;
        a3x /= n3; a3y /= n3; a3z /= n3;
        float* av = ws + OFF_AVEC;
        av[0]=a1x; av[1]=a1y; av[2]=a1z;
        av[3]=a2x; av[4]=a2y; av[5]=a2z;
        av[6]=a3x; av[7]=a3y; av[8]=a3z;
    }
    if (lane == 1) {
        const int* cnt = (const int*)(ws + OFF_BCNT);
        int* ofs = (int*)(ws + OFF_BOFS);
        int* fil = (int*)(ws + OFF_BFIL);
        int acc = 0;
        for (int i = 0; i < 64; ++i) { ofs[i] = acc; fil[i] = acc; acc += cnt[i]; }
        ofs[64] = acc;
    }
}

// ---------------- prep C+scatter: feat_down, counting-sort by x-bin ----------------
__global__ __launch_bounds__(256) void prep_cs_kernel(float* __restrict__ ws)
{
    const int n = blockIdx.x * 256 + threadIdx.x;
    const float* av = ws + OFF_AVEC;
    float4 v = ((const float4*)(ws + OFF_P4))[n];
    float vn = sqrtf(v.w);
    float den = vn + EPSF;
    float f1 = (v.x*av[0] + v.y*av[1] + v.z*av[2]) / den;
    float f2 = (v.x*av[3] + v.y*av[4] + v.z*av[5]) / den;
    float f3 = (v.x*av[6] + v.y*av[7] + v.z*av[8]) / den;
    ((float4*)(ws + OFF_FEATDN))[n] = make_float4(f1, f2, f3, vn);

    int pos = atomicAdd((int*)(ws + OFF_BFIL) + bin9(v.x), 1);
    ((float4*)(ws + OFF_P4S))[pos] = make_float4(v.x, v.y, v.z, __int_as_float(n));
}

// ---------------- per-window x bounds (8 windows of 1024 sorted slots) ----------------
__global__ __launch_bounds__(256) void bounds_kernel(float* __restrict__ ws)
{
    const int w = blockIdx.x, tid = threadIdx.x;
    const float4* p = (const float4*)(ws + OFF_P4S);
    float mn = 1e30f, mx = -1e30f;
    #pragma unroll
    for (int i = 0; i < 4; ++i) {
        float x = p[w*1024 + tid + i*256].x;
        mn = fminf(mn, x); mx = fmaxf(mx, x);
    }
    for (int j = 32; j > 0; j >>= 1) {
        mn = fminf(mn, __shfl_xor(mn, j));
        mx = fmaxf(mx, __shfl_xor(mx, j));
    }
    __shared__ float smn[4], smx[4];
    int wid = tid >> 6;
    if ((tid & 63) == 0) { smn[wid] = mn; smx[wid] = mx; }
    __syncthreads();
    if (tid == 0) {
        float MN = fminf(fminf(smn[0], smn[1]), fminf(smn[2], smn[3]));
        float MX = fmaxf(fmaxf(smx[0], smx[1]), fmaxf(smx[2], smx[3]));
        ws[OFF_TBND + 2*w] = MN;
        ws[OFF_TBND + 2*w + 1] = MX;
    }
}

// ---------------- weight prep: zeros, wt1 transpose, bf16 conv+MLP weights ----------------
__global__ __launch_bounds__(256) void wt_kernel(
    const float* __restrict__ c1w, const float* __restrict__ c2w,
    const float* __restrict__ c3w, const float* __restrict__ c4w,
    const float* __restrict__ gw0, const float* __restrict__ gw1,
    const float* __restrict__ gw2, const float* __restrict__ gw3,
    const float* __restrict__ gw4,
    float* __restrict__ ws)
{
    const int t = blockIdx.x * 256 + threadIdx.x;
    const int T = gridDim.x * 256;
    for (int m = t; m < 2944; m += T) ws[OFF_STATS + m] = 0.f;
    for (int m = t; m < 64; m += T) ((int*)(ws + OFF_BCNT))[m] = 0;
    for (int m = t; m < 64*4; m += T) { int o = m >> 2, c = m & 3; ws[OFF_WT1 + c*64 + o] = c1w[m]; }

    unsigned short* bw2 = (unsigned short*)(ws + OFF_BW2);
    for (int m = t; m < 128*64; m += T)   bw2[m] = f2bf(c2w[m]);
    unsigned short* bw3 = (unsigned short*)(ws + OFF_BW3);
    for (int m = t; m < 256*192; m += T)  bw3[m] = f2bf(c3w[m]);
    unsigned short* bw4 = (unsigned short*)(ws + OFF_BW4);
    for (int m = t; m < 1024*256; m += T) bw4[m] = f2bf(c4w[m]);

    unsigned short* gwt = (unsigned short*)(ws + OFF_GWT);
    for (int m = t; m < 2048; m += T) {          // gw0T padded [64][32]
        int o = m >> 5, i = m & 31;
        gwt[m] = (i < 4) ? f2bf(gw0[i*64 + o]) : (unsigned short)0;
    }
    const float* gsrc[4] = {gw1, gw2, gw3, gw4};
    for (int l = 0; l < 4; ++l) {
        const float* g = gsrc[l];
        unsigned short* dst = gwt + 2048 + l*4096;
        for (int m = t; m < 4096; m += T) { int o = m >> 6, i = m & 63; dst[m] = f2bf(g[i*64 + o]); }
    }
}

// ---------------- KNN v5 (measured best): center-out window sweep, LDS staging ----------------
// 512 blocks x 512 threads (8 waves); block owns 16 consecutive x-sorted queries;
// wave handles 2. Windows = 1024 sorted slots staged into LDS. Sweep starts at
// the block's own window, expands outward; side stops when for ALL queries
// (q.x - prefix_bound)^2 > kthd. Enqueue d<=kthd; u64 (dist,origIdx) keys make
// the selection exact under any scan order. Epilogue writes packed-bf16 feats.
__global__ __launch_bounds__(512) void knn_feat_kernel(
    const float4* __restrict__ p4,       // original order (feature phase)
    const float4* __restrict__ p4s,      // sorted by x-bin, w = as_float(origIdx)
    const float* __restrict__ wbnd,      // [8][2] window xmin,xmax
    uint2* __restrict__ feat_up)         // packed bf16 (f1,f2 | f3,vn)
{
    __shared__ __align__(16) float4 stage[1024];                 // 16 KB
    __shared__ unsigned long long queue[8][2][128];              // 16 KB
    __shared__ float sb[16], pmx[8], pmn[8];
    __shared__ int voteL, voteR, nextT;

    const int lane = threadIdx.x & 63;
    const int wid  = threadIdx.x >> 6;
    if (threadIdx.x < 16) sb[threadIdx.x] = wbnd[threadIdx.x];
    __syncthreads();
    if (threadIdx.x == 0) {
        float m = -1e30f;
        for (int w = 0; w < 8; ++w) { m = fmaxf(m, sb[2*w+1]); pmx[w] = m; }
        float n = 1e30f;
        for (int w = 7; w >= 0; --w) { n = fminf(n, sb[2*w]); pmn[w] = n; }
    }

    const int s0 = blockIdx.x * 16 + wid * 2;
    float4 qa = p4s[s0];
    float4 qb = p4s[s0 + 1];
    const int qi0 = __float_as_int(qa.w), qi1 = __float_as_int(qb.w);
    qa.w = fmaf(qa.x, qa.x, fmaf(qa.y, qa.y, qa.z * qa.z));
    qb.w = fmaf(qb.x, qb.x, fmaf(qb.y, qb.y, qb.z * qb.z));

    unsigned long long* Q0 = queue[wid][0];
    unsigned long long* Q1 = queue[wid][1];
    unsigned long long cur0 = ~0ull, cur1 = ~0ull;
    float kthd0 = __builtin_inff(), kthd1 = __builtin_inff();
    int qc0 = 0, qc1 = 0;

    const int w0 = blockIdx.x >> 6;      // 512 blocks / 8 windows = 64 blocks each
    int L = w0, R = w0, t = w0;

    for (;;) {
        __syncthreads();                                  // stage reuse + vote reset
        for (int i = threadIdx.x; i < 1024; i += 512) stage[i] = p4s[t*1024 + i];
        if (threadIdx.x == 0) { voteL = 0; voteR = 0; }
        __syncthreads();

        // per-wave window-level skip (every point in window has d >= gap^2)
        float wmn = sb[2*t], wmx = sb[2*t+1];
        float ga = fmaxf(fmaxf(qa.x - wmx, wmn - qa.x), 0.f);
        float gb = fmaxf(fmaxf(qb.x - wmx, wmn - qb.x), 0.f);
        if (!((ga*ga > kthd0) && (gb*gb > kthd1))) {
            #pragma unroll 2
            for (int sub = 0; sub < 1024; sub += 64) {
                float4 cd = stage[sub + lane];
                int ci = __float_as_int(cd.w);
                float cr = fmaf(cd.x, cd.x, fmaf(cd.y, cd.y, cd.z * cd.z));
                float dot0 = fmaf(qa.x, cd.x, fmaf(qa.y, cd.y, qa.z * cd.z));
                float d0   = fmaf(-2.f, dot0, qa.w) + cr;
                float dot1 = fmaf(qb.x, cd.x, fmaf(qb.y, cd.y, qb.z * cd.z));
                float d1   = fmaf(-2.f, dot1, qb.w) + cr;
                bool p0 = d0 <= kthd0, p1 = d1 <= kthd1;
                unsigned long long m0 = __ballot(p0);
                unsigned long long m1 = __ballot(p1);
                if (m0) {
                    int prefix = __builtin_amdgcn_mbcnt_hi((unsigned)(m0 >> 32),
                                  __builtin_amdgcn_mbcnt_lo((unsigned)m0, 0));
                    if (p0) Q0[qc0 + prefix] = ((unsigned long long)f2u(d0) << 32)
                                             | (unsigned long long)(unsigned)ci;
                    qc0 += __popcll(m0);
                    if (qc0 >= 64) {
                        qc0 -= 64;
                        cur0 = sort_merge(Q0[qc0 + lane], cur0, lane);
                        kthd0 = key_to_f(__shfl(cur0, 63));
                    }
                }
                if (m1) {
                    int prefix = __builtin_amdgcn_mbcnt_hi((unsigned)(m1 >> 32),
                                  __builtin_amdgcn_mbcnt_lo((unsigned)m1, 0));
                    if (p1) Q1[qc1 + prefix] = ((unsigned long long)f2u(d1) << 32)
                                             | (unsigned long long)(unsigned)ci;
                    qc1 += __popcll(m1);
                    if (qc1 >= 64) {
                        qc1 -= 64;
                        cur1 = sort_merge(Q1[qc1 + lane], cur1, lane);
                        kthd1 = key_to_f(__shfl(cur1, 63));
                    }
                }
            }
        }

        // vote: does this wave still need more windows on either side?
        if (lane == 0) {
            bool needL = false, needR = false;
            if (L > 0) {
                float p = pmx[L-1];
                float g0 = qa.x - p, g1 = qb.x - p;
                bool st0 = (g0 > 0.f) && (g0*g0 > kthd0);
                bool st1 = (g1 > 0.f) && (g1*g1 > kthd1);
                needL = !(st0 && st1);
            }
            if (R < 7) {
                float p = pmn[R+1];
                float g0 = p - qa.x, g1 = p - qb.x;
                bool st0 = (g0 > 0.f) && (g0*g0 > kthd0);
                bool st1 = (g1 > 0.f) && (g1*g1 > kthd1);
                needR = !(st0 && st1);
            }
            if (needL) atomicOr(&voteL, 1);
            if (needR) atomicOr(&voteR, 1);
        }
        __syncthreads();
        if (threadIdx.x == 0) {
            bool cL = (voteL != 0) && (L > 0);
            bool cR = (voteR != 0) && (R < 7);
            int nt = -1;
            if (cL && cR) nt = ((w0 - (L-1)) <= ((R+1) - w0)) ? (L-1) : (R+1);
            else if (cL) nt = L - 1;
            else if (cR) nt = R + 1;
            nextT = nt;
        }
        __syncthreads();
        t = nextT;
        if (t < 0) break;
        if (t < L) L = t; else R = t;
    }

    cur0 = sort_merge((lane < qc0) ? Q0[lane] : ~0ull, cur0, lane);
    cur1 = sort_merge((lane < qc1) ? Q1[lane] : ~0ull, cur1, lane);

    // features for both queries; lane k = k-th nearest (asc distance, idx tie-break)
    #pragma unroll 1
    for (int j = 0; j < 2; ++j) {
        unsigned long long cur = j ? cur1 : cur0;
        const int q = j ? qi1 : qi0;
        int nidx = (int)(unsigned)(cur & 0xFFFFFFFFu);
        float4 np = p4[nidx];
        float ox = __shfl(np.x, 0), oy = __shfl(np.y, 0), oz = __shfl(np.z, 0);
        float pcx = np.x - ox, pcy = np.y - oy, pcz = np.z - oz;
        float vn = sqrtf(pcx*pcx + pcy*pcy + pcz*pcz);

        unsigned long long ak = ((unsigned long long)__float_as_uint(vn) << 32)
                              | (unsigned long long)(unsigned)(63 - lane);
        for (int s = 32; s > 0; s >>= 1) ak = u64max(ak, __shfl_xor(ak, s));
        int id1 = 63 - (int)(unsigned)(ak & 0xFFFFFFFFu);

        float a1x = __shfl(pcx, id1), a1y = __shfl(pcy, id1), a1z = __shfl(pcz, id1);
        float n1 = sqrtf(a1x*a1x + a1y*a1y + a1z*a1z) + EPSF;
        a1x /= n1; a1y /= n1; a1z /= n1;

        float sx = pcx, sy = pcy, sz = pcz;
        for (int s = 32; s > 0; s >>= 1) {
            sx += __shfl_xor(sx, s); sy += __shfl_xor(sy, s); sz += __shfl_xor(sz, s);
        }
        float a2x = sx * (1.f/64.f), a2y = sy * (1.f/64.f), a2z = sz * (1.f/64.f);
        float n2 = sqrtf(a2x*a2x + a2y*a2y + a2z*a2z) + EPSF;
        a2x /= n2; a2y /= n2; a2z /= n2;

        float a3x = a1x + 1.5f*a2x, a3y = a1y + 1.5f*a2y, a3z = a1z + 1.5f*a2z;
        float n3 = sqrtf(a3x*a3x + a3y*a3y + a3z*a3z) + EPSF;
        a3x /= n3; a3y /= n3; a3z /= n3;

        float den = vn + EPSF;
        float f1 = (pcx*a1x + pcy*a1y + pcz*a1z) / den;
        float f2 = (pcx*a2x + pcy*a2y + pcz*a2z) / den;
        float f3 = (pcx*a3x + pcy*a3y + pcz*a3z) / den;
        uint2 pk;
        pk.x = (unsigned)f2bf(f1) | ((unsigned)f2bf(f2) << 16);
        pk.y = (unsigned)f2bf(f3) | ((unsigned)f2bf(vn) << 16);
        feat_up[q*64 + lane] = pk;
    }
}

// ---------------- 5-layer MLP via bf16 MFMA + max over K ----------------
// feat_up is packed bf16 (uint2). Epilogue writes emb_up's RAW-RESHAPE view
// into conv3's B operand: (point q, feature f) -> xb3[((q&127)*64+f)*192 + (q>>7)].
#define BROW 72
__global__ __launch_bounds__(256) void mlp_kernel(
    const uint2* __restrict__ feat_up,
    const unsigned short* __restrict__ gwt,
    unsigned short* __restrict__ xb3)
{
    __shared__ __align__(16) unsigned short Blds[4][64 * BROW];
    const int lane = threadIdx.x & 63;
    const int wid  = threadIdx.x >> 6;
    const int q = blockIdx.x * 4 + wid;
    const int c = lane & 15, g = lane >> 4;
    unsigned short* B = Blds[wid];

    {
        uint2 p0 = feat_up[q*64 + lane];
        *(uint2*)&B[lane*BROW] = p0;
        *(uint2*)&B[lane*BROW + 4] = make_uint2(0, 0);
        uint4 z4 = make_uint4(0, 0, 0, 0);
        *(uint4*)&B[lane*BROW + 8]  = z4;
        *(uint4*)&B[lane*BROW + 16] = z4;
        *(uint4*)&B[lane*BROW + 24] = z4;
    }

    const unsigned short* Wl[5] = {gwt, gwt + 2048, gwt + 6144, gwt + 10240, gwt + 14336};
    f32x4 acc[4][4];

    for (int layer = 0; layer < 5; ++layer) {
        const int wstride = (layer == 0) ? 32 : 64;
        const int nks = (layer == 0) ? 1 : 2;
        #pragma unroll
        for (int mb = 0; mb < 4; ++mb)
            #pragma unroll
            for (int nb = 0; nb < 4; ++nb)
                acc[mb][nb] = (f32x4){0.f, 0.f, 0.f, 0.f};

        for (int ks = 0; ks < nks; ++ks) {
            bf16x8 af[4], bf[4];
            #pragma unroll
            for (int mb = 0; mb < 4; ++mb)
                af[mb] = *(const bf16x8*)(Wl[layer] + (mb*16 + c)*wstride + ks*32 + g*8);
            #pragma unroll
            for (int nb = 0; nb < 4; ++nb)
                bf[nb] = *(const bf16x8*)&B[(nb*16 + c)*BROW + ks*32 + g*8];
            #pragma unroll
            for (int mb = 0; mb < 4; ++mb)
                #pragma unroll
                for (int nb = 0; nb < 4; ++nb)
                    acc[mb][nb] = __builtin_amdgcn_mfma_f32_16x16x32_bf16(af[mb], bf[nb], acc[mb][nb], 0, 0, 0);
        }

        if (layer < 4) {
            #pragma unroll
            for (int mb = 0; mb < 4; ++mb) {
                #pragma unroll
                for (int nb = 0; nb < 4; ++nb) {
                    f32x4 a = acc[mb][nb];
                    float r0 = fmaxf(a[0], 0.f), r1 = fmaxf(a[1], 0.f);
                    float r2 = fmaxf(a[2], 0.f), r3 = fmaxf(a[3], 0.f);
                    uint2 pw;
                    pw.x = (unsigned)f2bf(r0) | ((unsigned)f2bf(r1) << 16);
                    pw.y = (unsigned)f2bf(r2) | ((unsigned)f2bf(r3) << 16);
                    *(uint2*)&B[(nb*16 + c)*BROW + mb*16 + g*4] = pw;
                }
            }
        }
    }

    const int cc = q >> 7;
    const int pbase = (q & 127) << 6;
    #pragma unroll
    for (int mb = 0; mb < 4; ++mb) {
        float v[4];
        #pragma unroll
        for (int r = 0; r < 4; ++r)
            v[r] = fmaxf(fmaxf(fmaxf(acc[mb][0][r], acc[mb][1][r]),
                               fmaxf(acc[mb][2][r], acc[mb][3][r])), 0.f);
        #pragma unroll
        for (int mask = 1; mask <= 8; mask <<= 1)
            #pragma unroll
            for (int r = 0; r < 4; ++r)
                v[r] = fmaxf(v[r], __shfl_xor(v[r], mask));
        if (c == 0) {
            #pragma unroll
            for (int r = 0; r < 4; ++r) {
                const int f = mb*16 + g*4 + r;
                xb3[(size_t)(pbase + f) * 192 + cc] = f2bf(v[r]);
            }
        }
    }
}

// ---------------- conv1 (fp32 GEMV, K=4) with output stats ----------------
__global__ __launch_bounds__(256) void conv1_kernel(
    const float* __restrict__ x, const float* __restrict__ wt,
    const float* __restrict__ bias, float* __restrict__ y,
    float* __restrict__ stout)
{
    const int tid = threadIdx.x;
    const int p  = blockIdx.x * 256 + tid;
    const int o0 = blockIdx.y * 32;
    float acc[32];
    #pragma unroll
    for (int u = 0; u < 32; ++u) acc[u] = bias[o0 + u];
    #pragma unroll
    for (int c = 0; c < 4; ++c) {
        float xv = x[c * NPTS + p];
        const float* wr = wt + c * 64 + o0;
        #pragma unroll
        for (int u = 0; u < 32; ++u) acc[u] = fmaf(xv, wr[u], acc[u]);
    }
    #pragma unroll
    for (int u = 0; u < 32; ++u) y[(o0 + u) * NPTS + p] = acc[u];

    __shared__ float ps[4][32], pss[4][32];
    const int wid = tid >> 6, lane = tid & 63;
    #pragma unroll
    for (int u = 0; u < 32; ++u) {
        float s = acc[u], ss = acc[u] * acc[u];
        for (int j = 32; j > 0; j >>= 1) { s += __shfl_xor(s, j); ss += __shfl_xor(ss, j); }
        if (lane == 0) { ps[wid][u] = s; pss[wid][u] = ss; }
    }
    __syncthreads();
    if (tid < 32) {
        float S  = ps[0][tid] + ps[1][tid] + ps[2][tid] + ps[3][tid];
        float SS = pss[0][tid] + pss[1][tid] + pss[2][tid] + pss[3][tid];
        atomicAdd(&stout[o0 + tid], S);
        atomicAdd(&stout[64 + o0 + tid], SS);
    }
}

// ---------------- bnpack: y fp32 [C][N] -> BN+ReLU -> bf16 xb[p][stride] at col offset ----------------
__global__ __launch_bounds__(256) void bnpack_kernel(
    const float* __restrict__ y, const float* __restrict__ st,
    const float* __restrict__ gam, const float* __restrict__ bet,
    int C, int stride, int coff, unsigned short* __restrict__ xb)
{
    __shared__ float sc[256], sh[256];
    __shared__ __align__(16) unsigned short tile[64][264];
    const int tid = threadIdx.x;
    for (int cc = tid; cc < C; cc += 256) {
        float mu  = st[cc] * (1.f / 8192.f);
        float var = st[C + cc] * (1.f / 8192.f) - mu * mu;
        float s = gam[cc] / sqrtf(var + 1e-5f);
        sc[cc] = s; sh[cc] = bet[cc] - mu * s;
    }
    __syncthreads();
    const int pl = tid & 63, g = tid >> 6;
    const int p = blockIdx.x * 64 + pl;
    for (int c0 = g * 8; c0 < C; c0 += 32) {
        unsigned pk[4];
        #pragma unroll
        for (int h = 0; h < 4; ++h) {
            float v0 = fmaxf(fmaf(y[(c0 + 2*h    ) * NPTS + p], sc[c0 + 2*h    ], sh[c0 + 2*h    ]), 0.f);
            float v1 = fmaxf(fmaf(y[(c0 + 2*h + 1) * NPTS + p], sc[c0 + 2*h + 1], sh[c0 + 2*h + 1]), 0.f);
            pk[h] = (unsigned)f2bf(v0) | ((unsigned)f2bf(v1) << 16);
        }
        *(uint4*)&tile[pl][c0] = make_uint4(pk[0], pk[1], pk[2], pk[3]);
    }
    __syncthreads();
    const int cpr = C >> 3;
    const int nch = 64 * cpr;
    for (int idx = tid; idx < nch; idx += 256) {
        int r = idx / cpr, cc = (idx - r * cpr) * 8;
        *(uint4*)&xb[(size_t)(blockIdx.x * 64 + r) * stride + coff + cc] = *(uint4*)&tile[r][cc];
    }
}

// ---------------- conv via MFMA: y[M][N] = A[M][K](bf16) x Xb[N][K](bf16)^T + bias ----------------
__global__ __launch_bounds__(256) void conv_mfma_kernel(
    const unsigned short* __restrict__ A, const unsigned short* __restrict__ Bx,
    const float* __restrict__ bias, int K, int M,
    float* __restrict__ y, float* __restrict__ stout)
{
    const int lane = threadIdx.x & 63;
    const int w = threadIdx.x >> 6;
    const int n0 = blockIdx.x * 256 + w * 64;
    const int m0 = blockIdx.y * 64;
    const int c = lane & 15, g = lane >> 4;

    f32x4 acc[4][4];
    #pragma unroll
    for (int mt = 0; mt < 4; ++mt)
        #pragma unroll
        for (int nt = 0; nt < 4; ++nt)
            acc[mt][nt] = (f32x4){0.f, 0.f, 0.f, 0.f};

    for (int k0 = 0; k0 < K; k0 += 32) {
        bf16x8 af[4], bf[4];
        #pragma unroll
        for (int mt = 0; mt < 4; ++mt)
            af[mt] = *(const bf16x8*)(A + (size_t)(m0 + mt*16 + c) * K + k0 + g*8);
        #pragma unroll
        for (int nt = 0; nt < 4; ++nt)
            bf[nt] = *(const bf16x8*)(Bx + (size_t)(n0 + nt*16 + c) * K + k0 + g*8);
        #pragma unroll
        for (int mt = 0; mt < 4; ++mt)
            #pragma unroll
            for (int nt = 0; nt < 4; ++nt)
                acc[mt][nt] = __builtin_amdgcn_mfma_f32_16x16x32_bf16(af[mt], bf[nt], acc[mt][nt], 0, 0, 0);
    }

    #pragma unroll
    for (int mt = 0; mt < 4; ++mt) {
        float s[4], ss[4];
        #pragma unroll
        for (int r = 0; r < 4; ++r) {
            const int o = m0 + mt*16 + g*4 + r;
            const float bv = bias[o];
            float sum = 0.f, sq = 0.f;
            #pragma unroll
            for (int nt = 0; nt < 4; ++nt) {
                float v = acc[mt][nt][r] + bv;
                y[(size_t)o * NPTS + n0 + nt*16 + c] = v;
                sum += v; sq += v * v;
            }
            s[r] = sum; ss[r] = sq;
        }
        #pragma unroll
        for (int mask = 1; mask <= 8; mask <<= 1)
            #pragma unroll
            for (int r = 0; r < 4; ++r) {
                s[r]  += __shfl_xor(s[r],  mask);
                ss[r] += __shfl_xor(ss[r], mask);
            }
        if (c == 0) {
            #pragma unroll
            for (int r = 0; r < 4; ++r) {
                const int o = m0 + mt*16 + g*4 + r;
                atomicAdd(&stout[o], s[r]);
                atomicAdd(&stout[M + o], ss[r]);
            }
        }
    }
}

// ---------------- final BN + ReLU (in place on d_out) ----------------
__global__ __launch_bounds__(256) void bnrelu_kernel(
    const float* y, const float* __restrict__ st,
    const float* __restrict__ g, const float* __restrict__ b,
    float* out, int C)
{
    int idx = blockIdx.x * 256 + threadIdx.x;
    int c = idx >> 13;   // N = 8192
    float mu  = st[c] * (1.f / 8192.f);
    float var = st[C + c] * (1.f / 8192.f) - mu * mu;
    float scale = g[c] / sqrtf(var + 1e-5f);
    float v = fmaf(y[idx] - mu, scale, b[c]);
    out[idx] = fmaxf(v, 0.f);
}

extern "C" void kernel_launch(void* const* d_in, const int* in_sizes, int n_in,
                              void* d_out, int out_size, void* d_ws, size_t ws_size,
                              hipStream_t stream) {
    const float* points = (const float*)d_in[0];
    const float* gw0 = (const float*)d_in[1];
    const float* gw1 = (const float*)d_in[2];
    const float* gw2 = (const float*)d_in[3];
    const float* gw3 = (const float*)d_in[4];
    const float* gw4 = (const float*)d_in[5];
    const float* c1w = (const float*)d_in[6];  const float* c1b = (const float*)d_in[7];
    const float* bn1g = (const float*)d_in[8]; const float* bn1b = (const float*)d_in[9];
    const float* c2w = (const float*)d_in[10]; const float* c2b = (const float*)d_in[11];
    const float* bn2g = (const float*)d_in[12];const float* bn2b = (const float*)d_in[13];
    const float* c3w = (const float*)d_in[14]; const float* c3b = (const float*)d_in[15];
    const float* bn3g = (const float*)d_in[16];const float* bn3b = (const float*)d_in[17];
    const float* c4w = (const float*)d_in[18]; const float* c4b = (const float*)d_in[19];
    const float* bn4g = (const float*)d_in[20];const float* bn4b = (const float*)d_in[21];

    float* ws = (float*)d_ws;
    float* featdn = ws + OFF_FEATDN;
    float* y1 = ws + OFF_Y1; float* y2 = ws + OFF_Y2; float* y3 = ws + OFF_Y3;
    float* s1 = ws + OFF_STATS + 0;
    float* s2 = ws + OFF_STATS + 128;
    float* s3 = ws + OFF_STATS + 384;
    float* s4 = ws + OFF_STATS + 896;
    float* wt1 = ws + OFF_WT1;
    const unsigned short* gwt = (const unsigned short*)(ws + OFF_GWT);
    const unsigned short* bw2 = (const unsigned short*)(ws + OFF_BW2);
    const unsigned short* bw3 = (const unsigned short*)(ws + OFF_BW3);
    const unsigned short* bw4 = (const unsigned short*)(ws + OFF_BW4);
    unsigned short* xb1 = (unsigned short*)(ws + OFF_XB1);
    unsigned short* xb3 = (unsigned short*)(ws + OFF_XB3);
    unsigned short* xb4 = (unsigned short*)(ws + OFF_XB4);
    uint2* featup = (uint2*)(ws + OFF_FEATUP);
    float* outp = (float*)d_out;

    wt_kernel<<<256, 256, 0, stream>>>(c1w, c2w, c3w, c4w, gw0, gw1, gw2, gw3, gw4, ws);
    prep_a_kernel<<<32, 256, 0, stream>>>(points, ws);
    prep_b_kernel<<<1, 64, 0, stream>>>(points, ws);
    prep_cs_kernel<<<32, 256, 0, stream>>>(ws);
    bounds_kernel<<<8, 256, 0, stream>>>(ws);

    knn_feat_kernel<<<512, 512, 0, stream>>>(
        (const float4*)(ws + OFF_P4), (const float4*)(ws + OFF_P4S),
        ws + OFF_TBND, featup);
    mlp_kernel<<<2048, 256, 0, stream>>>(featup, gwt, xb3);

    conv1_kernel<<<dim3(32, 2), 256, 0, stream>>>(featdn, wt1, c1b, y1, s1);
    bnpack_kernel<<<128, 256, 0, stream>>>(y1, s1, bn1g, bn1b, 64, 64, 0, xb1);
    conv_mfma_kernel<<<dim3(32, 2), 256, 0, stream>>>(bw2, xb1, c2b, 64, 128, y2, s2);
    bnpack_kernel<<<128, 256, 0, stream>>>(y2, s2, bn2g, bn2b, 128, 192, 64, xb3);
    conv_mfma_kernel<<<dim3(32, 4), 256, 0, stream>>>(bw3, xb3, c3b, 192, 256, y3, s3);
    bnpack_kernel<<<128, 256, 0, stream>>>(y3, s3, bn3g, bn3b, 256, 256, 0, xb4);
    conv_mfma_kernel<<<dim3(32, 16), 256, 0, stream>>>(bw4, xb4, c4b, 256, 1024, outp, s4);
    bnrelu_kernel<<<1024*32, 256, 0, stream>>>(outp, s4, bn4g, bn4b, outp, 1024);
}